// Round 1
// 885.149 us; speedup vs baseline: 1.0780x; 1.0780x over previous
//
#include <hip/hip_runtime.h>
#include <hip/hip_bf16.h>
#include <stdint.h>

// ---------------------------------------------------------------------------
// GraphAttentionLayer: out = softmax(lrelu(s1_i + s2_j)) @ h,  h = x @ W^T
// Round 4: replace the m97-style 128^2 GEMM (843 TF, MfmaUtil 38%, 3.3e7 LDS
// bank conflicts) with the 256^2 8-phase counted-vmcnt template (T1+T2+T3+T4+
// T5): 512 threads / 8 waves, BK=64, 128 KiB double-buffered LDS, XOR-swizzled
// LDS (pre-swizzled global source, linear global_load_lds dest), one
// s_waitcnt vmcnt(4) per K-tile, setprio(1) around each 16-MFMA quadrant.
// Rest of the pipeline (rank-1 logit factorization + bucketed sweep) unchanged.
// ---------------------------------------------------------------------------

typedef float  f32x4  __attribute__((ext_vector_type(4)));
typedef __bf16 bf16x8 __attribute__((ext_vector_type(8)));

#define AS1 __attribute__((address_space(1)))
#define AS3 __attribute__((address_space(3)))

constexpr int NB  = 8192;    // batch rows (i and j)
constexpr int DF  = 4096;    // feature dim
constexpr int CH  = 64;      // sweep chunk length
constexpr int NCH = NB / CH; // 128

constexpr int GK  = DF;      // GEMM K
constexpr int BKK = 64;      // GEMM K-tile
constexpr int NT2 = GK / BKK;

__device__ __forceinline__ uint16_t f2bf_u(float f) {   // RNE fp32 -> bf16
  union { float f; uint32_t u; } x; x.f = f;
  return (uint16_t)((x.u + 0x7FFFu + ((x.u >> 16) & 1u)) >> 16);
}
__device__ __forceinline__ float bfu2f(uint16_t v) {
  union { uint32_t u; float f; } x; x.u = ((uint32_t)v) << 16;
  return x.f;
}

// --------------------------- fp32 -> bf16 convert ---------------------------
__global__ __launch_bounds__(256) void cvt_f32_to_bf16(
    const float* __restrict__ in, uint16_t* __restrict__ out, int n4) {
  int idx = blockIdx.x * 256 + threadIdx.x;
  int stride = gridDim.x * 256;
  for (int i = idx; i < n4; i += stride) {
    float4 v = ((const float4*)in)[i];
    ushort4 o;
    o.x = f2bf_u(v.x); o.y = f2bf_u(v.y); o.z = f2bf_u(v.z); o.w = f2bf_u(v.w);
    ((ushort4*)out)[i] = o;
  }
}

// --------------------------- NT bf16 GEMM: 256^2 8-phase ---------------------
// C[M=8192][N=4096] = A[8192][4096] * B[4096][4096]^T, bf16 in/out, fp32 acc.
// LDS layout per buffer: A tile [256][64] then B tile [256][64] bf16.
// Swizzle: element_in_row ^= (row&7)<<3  (16-byte granule across 128-B row).
// global_load_lds dest stays linear; the global SOURCE chunk is pre-swizzled.

#define STAGE_A(tt, half) do {                                                 \
  const uint16_t* g0_ = Ag + (size_t)((half) * 128) * GK + (size_t)(tt) * BKK; \
  uint32_t d_ = ((uint32_t)((tt) & 1)) * 32768u + (uint32_t)(half) * 8192u +   \
                (uint32_t)wave * 512u;                                         \
  __builtin_amdgcn_global_load_lds((const AS1 void*)g0_,                       \
      (AS3 void*)(lds + d_), 16, 0, 0);                                        \
  __builtin_amdgcn_global_load_lds((const AS1 void*)(g0_ + (size_t)64 * GK),   \
      (AS3 void*)(lds + d_ + 4096u), 16, 0, 0);                                \
} while (0)

#define STAGE_B(tt, half) do {                                                 \
  const uint16_t* g0_ = Bg + (size_t)((half) * 128) * GK + (size_t)(tt) * BKK; \
  uint32_t d_ = ((uint32_t)((tt) & 1)) * 32768u + 16384u +                     \
                (uint32_t)(half) * 8192u + (uint32_t)wave * 512u;              \
  __builtin_amdgcn_global_load_lds((const AS1 void*)g0_,                       \
      (AS3 void*)(lds + d_), 16, 0, 0);                                        \
  __builtin_amdgcn_global_load_lds((const AS1 void*)(g0_ + (size_t)64 * GK),   \
      (AS3 void*)(lds + d_ + 4096u), 16, 0, 0);                                \
} while (0)

#define LDA(mh) do {                                                           \
  _Pragma("unroll") for (int mf = 0; mf < 4; ++mf)                             \
    _Pragma("unroll") for (int ks = 0; ks < 2; ++ks)                           \
      aF[mf][ks] = *(const bf16x8*)(lds + bufo +                               \
          (uint32_t)(wm * 128 + (mh) * 64 + mf * 16 + lr) * 64u +              \
          (uint32_t)((ks * 32 + lg * 8) ^ swl));                               \
} while (0)

#define LDB(nh) do {                                                           \
  _Pragma("unroll") for (int nf = 0; nf < 2; ++nf)                             \
    _Pragma("unroll") for (int ks = 0; ks < 2; ++ks)                           \
      bF[nf][ks] = *(const bf16x8*)(lds + bufo + 16384u +                      \
          (uint32_t)(wn * 64 + (nh) * 32 + nf * 16 + lr) * 64u +               \
          (uint32_t)((ks * 32 + lg * 8) ^ swl));                               \
} while (0)

#define MMA(mh, nh) do {                                                       \
  _Pragma("unroll") for (int mf = 0; mf < 4; ++mf)                             \
    _Pragma("unroll") for (int nf = 0; nf < 2; ++nf)                           \
      _Pragma("unroll") for (int ks = 0; ks < 2; ++ks)                         \
        acc[(mh) * 4 + mf][(nh) * 2 + nf] =                                    \
            __builtin_amdgcn_mfma_f32_16x16x32_bf16(aF[mf][ks], bF[nf][ks],    \
                acc[(mh) * 4 + mf][(nh) * 2 + nf], 0, 0, 0);                   \
} while (0)

__global__ __launch_bounds__(512, 2) void gemm_nt_8phase(
    const uint16_t* __restrict__ A, const uint16_t* __restrict__ B,
    uint16_t* __restrict__ C) {
  __shared__ uint16_t lds[65536];   // 128 KiB: [buf][A|B][256*64]

  const int tid  = threadIdx.x;
  const int wave = tid >> 6;
  const int lane = tid & 63;
  const int lr   = lane & 15;
  const int lg   = lane >> 4;        // 0..3
  const int wm   = wave >> 2;        // 0..1  (M half)
  const int wn   = wave & 3;         // 0..3  (N quarter)
  const int swl  = (lr & 7) << 3;    // read-side XOR swizzle (elements)

  // XCD-aware bijective swizzle over 512 blocks (512 % 8 == 0)
  const int bid = blockIdx.x;
  const int swz = (bid & 7) * 64 + (bid >> 3);
  const int bx  = swz & 15;          // N tile (16)
  const int by  = swz >> 4;          // M tile (32)
  const int rowBase = by * 256;
  const int colBase = bx * 256;

  // stage source: thread t covers LDS row sr, 16-B chunk (t&7); source chunk
  // is pre-swizzled so that linear LDS dest + swizzled read = identity.
  const int sr  = tid >> 3;                    // 0..63
  const int sch = (tid & 7) ^ (sr & 7);
  const uint16_t* Ag = A + (size_t)(rowBase + sr) * GK + sch * 8;
  const uint16_t* Bg = B + (size_t)(colBase + sr) * GK + sch * 8;

  f32x4 acc[8][4];
#pragma unroll
  for (int mf = 0; mf < 8; ++mf)
#pragma unroll
    for (int nf = 0; nf < 4; ++nf) acc[mf][nf] = (f32x4){0.f, 0.f, 0.f, 0.f};

  // prologue: tile0 {A0,B1,A1,B0} + tile1 {A0,B1}  (issue order matters for
  // the counted vmcnt)
  STAGE_A(0, 0);
  STAGE_B(0, 1);
  STAGE_A(0, 1);
  STAGE_B(0, 0);
  STAGE_A(1, 0);
  STAGE_B(1, 1);
  asm volatile("s_waitcnt vmcnt(4)" ::: "memory");   // tile0 fully landed
  __builtin_amdgcn_s_barrier();

  bf16x8 aF[4][2], bF[2][2];

  for (int t = 0; t < NT2; ++t) {
    const uint32_t bufo = ((uint32_t)(t & 1)) * 32768u;

    // ---- phase 1: quadrant (mh0, nh0) ----
    LDA(0); LDB(0);
    if (t + 1 < NT2) STAGE_A(t + 1, 1);   // A-half1(t+1) -> other buffer
    __builtin_amdgcn_s_barrier();
    __builtin_amdgcn_s_setprio(1);
    MMA(0, 0);
    __builtin_amdgcn_s_setprio(0);
    __builtin_amdgcn_s_barrier();

    // ---- phase 2: quadrant (mh0, nh1) — reuse aF ----
    LDB(1);
    if (t + 1 < NT2) STAGE_B(t + 1, 0);   // B-half0(t+1) -> other buffer
    __builtin_amdgcn_s_barrier();
    __builtin_amdgcn_s_setprio(1);
    MMA(0, 1);
    __builtin_amdgcn_s_setprio(0);
    __builtin_amdgcn_s_barrier();

    // ---- phase 3: quadrant (mh1, nh1) — reuse bF ----
    LDA(1);
    if (t + 2 < NT2) STAGE_A(t + 2, 0);   // A-half0(t+2) -> this buffer
                                          // (A0 consumed in phases 1-2)
    __builtin_amdgcn_s_barrier();
    __builtin_amdgcn_s_setprio(1);
    MMA(1, 1);
    __builtin_amdgcn_s_setprio(0);
    __builtin_amdgcn_s_barrier();

    // ---- phase 4: quadrant (mh1, nh0) — reuse aF ----
    LDB(0);
    if (t + 2 < NT2) STAGE_B(t + 2, 1);   // B-half1(t+2) -> this buffer
                                          // (B1 consumed in phases 2-3)
    __builtin_amdgcn_s_barrier();
    __builtin_amdgcn_s_setprio(1);
    MMA(1, 0);
    __builtin_amdgcn_s_setprio(0);
    if (t + 2 < NT2) {
      asm volatile("s_waitcnt vmcnt(4)" ::: "memory");  // next tile landed;
                                                        // keep 2 halves in flight
    } else if (t + 1 < NT2) {
      asm volatile("s_waitcnt vmcnt(0)" ::: "memory");  // drain for last tile
    }
    __builtin_amdgcn_s_barrier();
  }

  // epilogue: C/D layout col = lane&15, row = (lane>>4)*4 + reg
  const int r0 = rowBase + wm * 128 + lg * 4;
  const int c0 = colBase + wn * 64 + lr;
#pragma unroll
  for (int mf = 0; mf < 8; ++mf)
#pragma unroll
    for (int nf = 0; nf < 4; ++nf)
#pragma unroll
      for (int e = 0; e < 4; ++e)
        C[(size_t)(r0 + mf * 16 + e) * (size_t)DF + (c0 + nf * 16)] =
            f2bf_u(acc[mf][nf][e]);
}

// --------------------------- s1/s2: h @ a1, h @ a2 --------------------------
__global__ __launch_bounds__(256) void s12_kernel(
    const uint16_t* __restrict__ h, const float* __restrict__ a,
    float* __restrict__ s1, float* __restrict__ s2) {
  const int wave = threadIdx.x >> 6, lane = threadIdx.x & 63;
  const int row = blockIdx.x * 4 + wave;
  const uint32_t* hr = (const uint32_t*)(h + (size_t)row * DF);
  float d1 = 0.f, d2 = 0.f;
#pragma unroll 4
  for (int it = 0; it < DF / 128; it++) {
    int u = it * 64 + lane;
    uint32_t hv = hr[u];
    float lo = bfu2f((uint16_t)hv), hi = bfu2f((uint16_t)(hv >> 16));
    int k = 2 * u;
    d1 += a[k] * lo + a[k + 1] * hi;
    d2 += a[DF + k] * lo + a[DF + k + 1] * hi;
  }
  for (int off = 32; off > 0; off >>= 1) {
    d1 += __shfl_down(d1, off, 64);
    d2 += __shfl_down(d2, off, 64);
  }
  if (lane == 0) { s1[row] = d1; s2[row] = d2; }
}

// --------------------------- rank sort of s2 (descending) -------------------
__global__ __launch_bounds__(256) void rank_kernel(
    const float* __restrict__ s2, int* __restrict__ pi,
    float* __restrict__ s2sorted) {
  __shared__ float ld[NB];
  for (int idx = threadIdx.x; idx < NB; idx += 256) ld[idx] = s2[idx];
  __syncthreads();
  const int j = blockIdx.x * 256 + threadIdx.x;
  const float v = ld[j];
  int cnt = 0;
  for (int q = 0; q < NB / 4; q++) {
    float4 u = ((const float4*)ld)[q];
    int jj = q * 4;
    cnt += (u.x > v) || (u.x == v && (jj + 0) < j);
    cnt += (u.y > v) || (u.y == v && (jj + 1) < j);
    cnt += (u.z > v) || (u.z == v && (jj + 2) < j);
    cnt += (u.w > v) || (u.w == v && (jj + 3) < j);
  }
  pi[cnt] = j;
  s2sorted[cnt] = v;
}

// --------------------------- c_i = #{j : s2_j > -s1_i} ----------------------
__global__ __launch_bounds__(256) void count_kernel(
    const float* __restrict__ s1, const float* __restrict__ s2,
    int* __restrict__ ci) {
  __shared__ float ld[NB];
  for (int idx = threadIdx.x; idx < NB; idx += 256) ld[idx] = s2[idx];
  __syncthreads();
  const int i = blockIdx.x * 256 + threadIdx.x;
  const float thr = -s1[i];
  int cnt = 0;
  for (int q = 0; q < NB / 4; q++) {
    float4 u = ((const float4*)ld)[q];
    cnt += (u.x > thr) + (u.y > thr) + (u.z > thr) + (u.w > thr);
  }
  ci[i] = cnt;
}

// --------------------------- scalar weights + prefix sums -------------------
__global__ __launch_bounds__(256) void scan_kernel(
    const float* __restrict__ s2sorted, float* __restrict__ Sb,
    float* __restrict__ Sc, float* __restrict__ wbg, float* __restrict__ wcg) {
  __shared__ float pb[256], pc[256];
  const int t = threadIdx.x;
  float sb = 0.f, sc = 0.f;
  for (int c = t * 32; c < t * 32 + 32; c++) {
    float s = s2sorted[c];
    float wb = __expf(0.2f * s), wc = __expf(s);
    wbg[c] = wb; wcg[c] = wc;
    sb += wb; sc += wc;
  }
  pb[t] = sb; pc[t] = sc;
  __syncthreads();
  if (t == 0) {
    float rb = 0.f, rc = 0.f;
    for (int q = 0; q < 256; q++) {
      float tb = pb[q], tc = pc[q];
      pb[q] = rb; pc[q] = rc;
      rb += tb; rc += tc;
    }
    Sb[0] = 0.f; Sc[0] = 0.f;
    Sb[NB] = rb; Sc[NB] = rc;
  }
  __syncthreads();
  float rb = pb[t], rc = pc[t];
  for (int c = t * 32; c < t * 32 + 32; c++) {
    rb += wbg[c]; rc += wcg[c];
    if (c + 1 < NB) { Sb[c + 1] = rb; Sc[c + 1] = rc; }
  }
}

// --------------------------- bucket machinery -------------------------------
__global__ __launch_bounds__(256) void zero_hist(int* __restrict__ hist) {
  int t = blockIdx.x * 256 + threadIdx.x;
  if (t <= NB) hist[t] = 0;
}

// per-i scalars f1,f2 and histogram of boundary buckets (bucket = c_i)
__global__ __launch_bounds__(256) void finalize_kernel(
    const float* __restrict__ s1, const int* __restrict__ ci,
    const float* __restrict__ Sb, const float* __restrict__ Sc,
    float* __restrict__ f1, float* __restrict__ f2, int* __restrict__ hist) {
  const int i = blockIdx.x * 256 + threadIdx.x;
  const float s1i = s1[i];
  const int c = ci[i];
  const float q1 = __expf(0.2f * s1i), q2 = __expf(s1i);
  const float l = q1 * (Sb[NB] - Sb[c]) + q2 * Sc[c];
  f1[i] = q1 / l;
  f2[i] = q2 / l;
  atomicAdd(&hist[c], 1);
}

// exclusive scan of hist[0..NB] -> istart[0..NB+1]; cursor = copy
__global__ __launch_bounds__(256) void bucket_scan(
    const int* __restrict__ hist, int* __restrict__ istart,
    int* __restrict__ cursor) {
  __shared__ int ps[256];
  const int t = threadIdx.x;
  const int lo = t * 33;
  const int hi = min(lo + 33, NB + 1);
  int s = 0;
  for (int b = lo; b < hi; b++) s += hist[b];
  ps[t] = s;
  __syncthreads();
  if (t == 0) {
    int r = 0;
    for (int q = 0; q < 256; q++) { int v = ps[q]; ps[q] = r; r += v; }
  }
  __syncthreads();
  int r = ps[t];
  for (int b = lo; b < hi; b++) { istart[b] = r; cursor[b] = r; r += hist[b]; }
  if (t == 255) istart[NB + 1] = r;
}

__global__ __launch_bounds__(256) void scatter_kernel(
    const int* __restrict__ ci, int* __restrict__ cursor,
    int* __restrict__ ilist) {
  const int i = blockIdx.x * 256 + threadIdx.x;
  const int b = ci[i];
  const int pos = atomicAdd(&cursor[b], 1);
  ilist[pos] = i;
}

// --------------------------- pass1: chunk totals ----------------------------
__global__ __launch_bounds__(256) void pass1_kernel(
    const uint16_t* __restrict__ h, const int* __restrict__ pi,
    const float* __restrict__ wbg, const float* __restrict__ wcg,
    float* __restrict__ Bct, float* __restrict__ Cct) {
  __shared__ int   pj[CH];
  __shared__ float wb[CH], wc[CH];
  const int t  = threadIdx.x;
  const int cb = blockIdx.x;
  const int k  = blockIdx.y;
  if (t < CH) {
    int g = k * CH + t;
    pj[t] = pi[g]; wb[t] = wbg[g]; wc[t] = wcg[g];
  }
  __syncthreads();
  const int n0 = cb * 512 + t * 2;
  float b0 = 0.f, b1 = 0.f, c0 = 0.f, c1 = 0.f;
#pragma unroll 4
  for (int c = 0; c < CH; c++) {
    uint32_t hv = *(const uint32_t*)(h + (size_t)pj[c] * DF + n0);
    float h0 = bfu2f((uint16_t)hv), h1 = bfu2f((uint16_t)(hv >> 16));
    b0 += wb[c] * h0; b1 += wb[c] * h1;
    c0 += wc[c] * h0; c1 += wc[c] * h1;
  }
  *(float2*)(Bct + (size_t)k * DF + n0) = make_float2(b0, b1);
  *(float2*)(Cct + (size_t)k * DF + n0) = make_float2(c0, c1);
}

// --------------------------- chunk offset scan (per column) -----------------
__global__ __launch_bounds__(256) void boff_kernel(
    const float* __restrict__ Bct, const float* __restrict__ Cct,
    float* __restrict__ Boff, float* __restrict__ Coff) {
  const int n = blockIdx.x * 256 + threadIdx.x;
  float ob = 0.f, oc = 0.f;
  for (int k = 0; k < NCH; k++) {
    Boff[(size_t)k * DF + n] = ob;
    Coff[(size_t)k * DF + n] = oc;
    ob += Bct[(size_t)k * DF + n];
    oc += Cct[(size_t)k * DF + n];
  }
  Boff[(size_t)NCH * DF + n] = ob;   // = A_n
  Coff[(size_t)NCH * DF + n] = oc;
}

// --------------------------- pass2: sweep + direct emission -----------------
__global__ __launch_bounds__(256) void pass2_kernel(
    const uint16_t* __restrict__ h, const int* __restrict__ pi,
    const float* __restrict__ wbg, const float* __restrict__ wcg,
    const float* __restrict__ Boff, const float* __restrict__ Coff,
    const int* __restrict__ istart, const int* __restrict__ ilist,
    const float* __restrict__ f1, const float* __restrict__ f2,
    float* __restrict__ out) {
  __shared__ int   pj[CH];
  __shared__ float wb[CH], wc[CH];
  __shared__ int   se[CH + 2];
  const int t  = threadIdx.x;
  const int cb = blockIdx.x;
  const int k  = blockIdx.y;
  if (t < CH) {
    int g = k * CH + t;
    pj[t] = pi[g]; wb[t] = wbg[g]; wc[t] = wcg[g];
  }
  if (t < CH + 2) se[t] = istart[k * CH + t];
  __syncthreads();
  const int n0 = cb * 512 + t * 2;
  const float2 An = *(const float2*)(Boff + (size_t)NCH * DF + n0);
  const float2 Bo = *(const float2*)(Boff + (size_t)k * DF + n0);
  const float2 Co = *(const float2*)(Coff + (size_t)k * DF + n0);
  float b0 = Bo.x, b1 = Bo.y, c0 = Co.x, c1 = Co.y;

  if (k == 0) {   // bucket 0: boundary before any j (c_i == 0)
    for (int idx = se[0]; idx < se[1]; idx++) {
      const int i = ilist[idx];
      const float fa = f1[i];
      *(float2*)(out + (size_t)i * DF + n0) = make_float2(fa * An.x, fa * An.y);
    }
  }
  for (int c = 0; c < CH; c++) {
    uint32_t hv = *(const uint32_t*)(h + (size_t)pj[c] * DF + n0);
    float h0 = bfu2f((uint16_t)hv), h1 = bfu2f((uint16_t)(hv >> 16));
    b0 += wb[c] * h0; b1 += wb[c] * h1;
    c0 += wc[c] * h0; c1 += wc[c] * h1;
    const int e0 = se[c + 1], e1 = se[c + 2];
    for (int idx = e0; idx < e1; idx++) {
      const int i = ilist[idx];
      const float fa = f1[i], fb = f2[i];
      float o0 = fa * (An.x - b0) + fb * c0;
      float o1 = fa * (An.y - b1) + fb * c1;
      *(float2*)(out + (size_t)i * DF + n0) = make_float2(o0, o1);
    }
  }
}

// ---------------------------------------------------------------------------
extern "C" void kernel_launch(void* const* d_in, const int* in_sizes, int n_in,
                              void* d_out, int out_size, void* d_ws, size_t ws_size,
                              hipStream_t stream) {
  const float* x = (const float*)d_in[0];   // [8192][4096] fp32
  const float* W = (const float*)d_in[1];   // [4096][4096] fp32
  const float* a = (const float*)d_in[2];   // [8192] fp32
  float* out = (float*)d_out;               // [8192][4096] fp32

  char* ws = (char*)d_ws;
  uint16_t* h = (uint16_t*)ws;                 // 64 MB
  char* sm = ws + 67108864;
  float* s1       = (float*)(sm);
  float* s2       = (float*)(sm + 65536);
  float* s2sorted = (float*)(sm + 131072);
  int*   pi       = (int*)  (sm + 196608);
  int*   ci       = (int*)  (sm + 262144);
  float* Sb       = (float*)(sm + 327680);     // NB+1 floats
  float* Sc       = (float*)(sm + 393216);
  float* wbg      = (float*)(sm + 458752);
  float* wcg      = (float*)(sm + 524288);
  float* f1       = (float*)(sm + 589824);
  float* f2       = (float*)(sm + 655360);
  int*   hist     = (int*)  (sm + 720896);     // NB+1 ints
  int*   istart   = (int*)  (sm + 786432);     // NB+2 ints
  int*   cursor   = (int*)  (sm + 851968);     // NB+1 ints
  int*   ilist    = (int*)  (sm + 917504);     // NB ints
  float* Bct      = (float*)(sm + 1048576);    // NCH*DF*4 = 2 MB
  float* Cct      = (float*)(sm + 3145728);    // 2 MB
  float* Boff     = (float*)(sm + 5242880);    // (NCH+1)*DF*4 ~ 2.02 MB
  float* Coff     = (float*)(sm + 7602176);    // ~2.02 MB (ends sm+9.96MB)
  char* base2 = ws + 67108864 + 10485760;      // staging (dead after gemm)
  uint16_t* xb = (uint16_t*)base2;             // 64 MB
  uint16_t* Wb = (uint16_t*)(base2 + 67108864);// 32 MB  (total ws ~169 MB)

  cvt_f32_to_bf16<<<1024, 256, 0, stream>>>(x, xb, (NB * DF) / 4);
  cvt_f32_to_bf16<<<1024, 256, 0, stream>>>(W, Wb, (DF * DF) / 4);

  // GEMM1: h[i][o] = sum_k x[i][k] W[o][k]   (M=8192, N=4096, K=4096)
  gemm_nt_8phase<<<(NB / 256) * (DF / 256), 512, 0, stream>>>(xb, Wb, h);

  zero_hist<<<33, 256, 0, stream>>>(hist);
  s12_kernel<<<NB / 4, 256, 0, stream>>>(h, a, s1, s2);
  rank_kernel<<<NB / 256, 256, 0, stream>>>(s2, pi, s2sorted);
  count_kernel<<<NB / 256, 256, 0, stream>>>(s1, s2, ci);
  scan_kernel<<<1, 256, 0, stream>>>(s2sorted, Sb, Sc, wbg, wcg);
  finalize_kernel<<<NB / 256, 256, 0, stream>>>(s1, ci, Sb, Sc, f1, f2, hist);
  bucket_scan<<<1, 256, 0, stream>>>(hist, istart, cursor);
  scatter_kernel<<<NB / 256, 256, 0, stream>>>(ci, cursor, ilist);

  pass1_kernel<<<dim3(DF / 512, NCH), 256, 0, stream>>>(h, pi, wbg, wcg, Bct, Cct);
  boff_kernel<<<DF / 256, 256, 0, stream>>>(Bct, Cct, Boff, Coff);
  pass2_kernel<<<dim3(DF / 512, NCH), 256, 0, stream>>>(
      h, pi, wbg, wcg, Boff, Coff, istart, ilist, f1, f2, out);
}